// Round 17
// baseline (137.411 us; speedup 1.0000x reference)
//
#include <hip/hip_runtime.h>

#define NN 100000
#define NE 1600000
#define D 64
#define BSHIFT 7
#define NPB 128                        // nodes per bucket
#define NBUCK ((NN + NPB - 1) / NPB)   // 782
#define NCHUNK 1000                    // edge chunks
#define CE (NE / NCHUNK)               // 1600 edges per chunk (exact)
#define BSTR (NBUCK + 1)               // basG row stride (783)
#define CAPC 2560                      // csr per-bucket capacity (mean 2046, 11-sigma)
#define NFC 1563                       // fcvt tile-groups (6250 16-node tiles / 4)
#define NXCD 8

typedef unsigned int uint32;
typedef __attribute__((ext_vector_type(8))) short bf16x8;
typedef __attribute__((ext_vector_type(4))) float f32x4;

__device__ __forceinline__ uint32 f2bf(float f) {   // round-to-nearest-even
    union { float f; uint32 i; } c; c.f = f;
    return (c.i + 0x7FFFu + ((c.i >> 16) & 1u)) >> 16;
}

__device__ __forceinline__ bf16x8 cvt8(const float* p) {
    float4 lo = *reinterpret_cast<const float4*>(p);
    float4 hi = *reinterpret_cast<const float4*>(p + 4);
    bf16x8 r;
    r[0] = (short)f2bf(lo.x); r[1] = (short)f2bf(lo.y);
    r[2] = (short)f2bf(lo.z); r[3] = (short)f2bf(lo.w);
    r[4] = (short)f2bf(hi.x); r[5] = (short)f2bf(hi.y);
    r[6] = (short)f2bf(hi.z); r[7] = (short)f2bf(hi.w);
    return r;
}

// intra-wave inclusive scan (64 lanes)
__device__ __forceinline__ int wave_iscan(int x, int lane) {
#pragma unroll
    for (int off = 1; off < 64; off <<= 1) {
        int y = __shfl_up(x, off);
        if (lane >= off) x += y;
    }
    return x;
}

// bijective chunked block->XCD swizzle [T1, m204]
__device__ __forceinline__ int swz_chunked(int bid, int nwg) {
    int q = nwg / NXCD, r = nwg % NXCD;
    int xcd = bid % NXCD, idx = bid / NXCD;
    return (xcd < r) ? xcd * (q + 1) + idx : r * (q + 1) + (xcd - r) * q + idx;
}

// ---------- FUSED: chunk-local bucket sort (blocks 0..NCHUNK-1) + fcvt ----------
__global__ __launch_bounds__(256) void build_kernel(const float* __restrict__ feat,
                                                    const float* __restrict__ W1,
                                                    unsigned short* __restrict__ fb,
                                                    const int* __restrict__ src,
                                                    const int* __restrict__ dst,
                                                    int* __restrict__ basG,
                                                    int* __restrict__ ebuf) {
    __shared__ int ebl[CE];                 // packed (src<<7 | localdst)
    __shared__ unsigned short bkt[CE];      // bucket id per staged edge
    __shared__ int cnt[NBUCK];              // per-bucket count, then scatter cursor
    __shared__ int sc[NBUCK + 1];           // exclusive scan of cnt
    __shared__ int wsum[4];
    const int bid = blockIdx.x;
    const int t = threadIdx.x;
    if (bid >= NCHUNK) {                   // ---- fcvt half ----
        const int wid = t >> 6;
        const int lane = t & 63;
        const int tile = (bid - NCHUNK) * 4 + wid;
        if (tile >= 6250) return;
        const int node0 = tile * 16;
        const int m = lane & 15;
        const int kg = lane >> 4;
        const float* frow = feat + (size_t)(node0 + m) * D + kg * 8;
        bf16x8 aF0 = cvt8(frow);
        bf16x8 aF1 = cvt8(frow + 32);
#pragma unroll
        for (int tt = 0; tt < 4; ++tt) {
            const float* wrow = W1 + (size_t)(tt * 16 + m) * D + kg * 8;
            bf16x8 bF0 = cvt8(wrow);
            bf16x8 bF1 = cvt8(wrow + 32);
            f32x4 acc = {0.f, 0.f, 0.f, 0.f};
            acc = __builtin_amdgcn_mfma_f32_16x16x32_bf16(aF0, bF0, acc, 0, 0, 0);
            acc = __builtin_amdgcn_mfma_f32_16x16x32_bf16(aF1, bF1, acc, 0, 0, 0);
            const int col = tt * 16 + m;
#pragma unroll
            for (int r = 0; r < 4; ++r)
                fb[(size_t)(node0 + kg * 4 + r) * D + col] = (unsigned short)f2bf(acc[r]);
        }
        return;
    }
    // ---- part half ----
    const int lane = t & 63;
    const int wid = t >> 6;
    for (int i = t; i < NBUCK; i += 256) cnt[i] = 0;
    __syncthreads();
    const int e0 = bid * CE;
    for (int i = t; i < CE; i += 256) {
        int d = dst[e0 + i], s = src[e0 + i];
        int b = d >> BSHIFT;
        ebl[i] = (s << BSHIFT) | (d & (NPB - 1));
        bkt[i] = (unsigned short)b;
        atomicAdd(&cnt[b], 1);
    }
    __syncthreads();
    // exclusive scan of cnt[0..781]: 4/thread + wave-shuffle scan (1 barrier)
    const int j0 = t * 4;
    int v0 = (j0 + 0 < NBUCK) ? cnt[j0 + 0] : 0;
    int v1 = (j0 + 1 < NBUCK) ? cnt[j0 + 1] : 0;
    int v2 = (j0 + 2 < NBUCK) ? cnt[j0 + 2] : 0;
    int v3 = (j0 + 3 < NBUCK) ? cnt[j0 + 3] : 0;
    int s0 = v0, s1 = s0 + v1, s2 = s1 + v2, s3 = s2 + v3;
    int x = wave_iscan(s3, lane);
    if (lane == 63) wsum[wid] = x;
    __syncthreads();
    int wpre = 0;
    for (int w = 0; w < wid; ++w) wpre += wsum[w];
    const int pre = x + wpre - s3;          // exclusive thread prefix
    if (j0 + 0 < NBUCK) sc[j0 + 0] = pre;
    if (j0 + 1 < NBUCK) sc[j0 + 1] = pre + s0;
    if (j0 + 2 < NBUCK) sc[j0 + 2] = pre + s1;
    if (j0 + 3 < NBUCK) sc[j0 + 3] = pre + s2;
    if (t == 0) sc[NBUCK] = CE;
    __syncthreads();
    // emit local prefix table (coalesced) + reset cnt as scatter cursor
    int* brow = basG + (size_t)bid * BSTR;
    for (int j = t; j < BSTR; j += 256) brow[j] = sc[j];
    for (int i = t; i < NBUCK; i += 256) cnt[i] = 0;
    __syncthreads();
    // scatter bucket-sorted into own chunk region (writes land in 6.4KB window)
    for (int i = t; i < CE; i += 256) {
        int b = bkt[i];
        int p = sc[b] + atomicAdd(&cnt[b], 1);
        ebuf[e0 + p] = ebl[i];
    }
}

// ---------- per-bucket: assemble segments, degrees/norm/rpd, bin to csr ----------
__global__ __launch_bounds__(256) void bucketize_kernel(const int* __restrict__ ebuf,
                                                        const int* __restrict__ basG,
                                                        int* __restrict__ csr,
                                                        uint32* __restrict__ rpd,
                                                        float* __restrict__ norm) {
    __shared__ int stage[CAPC];
    __shared__ int clo[NCHUNK];
    __shared__ int clen[NCHUNK];
    __shared__ int cpre[NCHUNK + 1];
    __shared__ int wsum[4];
    __shared__ int cnt[NPB];
    __shared__ int sc2[NPB + 1];
    __shared__ int lcur[NPB];
    const int b = swz_chunked(blockIdx.x, NBUCK);
    const int base = b << BSHIFT;
    const int t = threadIdx.x;
    const int lane = t & 63;
    const int wid = t >> 6;
    // 1) per-chunk segment ranges for this bucket
    for (int c = t; c < NCHUNK; c += 256) {
        int lo = basG[(size_t)c * BSTR + b];
        int hi = basG[(size_t)c * BSTR + b + 1];
        clo[c] = lo;
        clen[c] = hi - lo;
    }
    if (t < NPB) { cnt[t] = 0; lcur[t] = 0; }
    if (t == 0) sc2[0] = 0;
    __syncthreads();
    // 2) exclusive scan of clen[0..NCHUNK-1]: 4/thread + wave scan (1 barrier)
    const int c0 = t * 4;
    int w0 = (c0 + 0 < NCHUNK) ? clen[c0 + 0] : 0;
    int w1 = (c0 + 1 < NCHUNK) ? clen[c0 + 1] : 0;
    int w2 = (c0 + 2 < NCHUNK) ? clen[c0 + 2] : 0;
    int w3 = (c0 + 3 < NCHUNK) ? clen[c0 + 3] : 0;
    int u0 = w0, u1 = u0 + w1, u2 = u1 + w2, u3 = u2 + w3;
    int x = wave_iscan(u3, lane);
    if (lane == 63) wsum[wid] = x;
    __syncthreads();
    int wpre = 0;
    for (int w = 0; w < wid; ++w) wpre += wsum[w];
    const int pre = x + wpre - u3;
    if (c0 + 0 < NCHUNK) cpre[c0 + 0] = pre;
    if (c0 + 1 < NCHUNK) cpre[c0 + 1] = pre + u0;
    if (c0 + 2 < NCHUNK) cpre[c0 + 2] = pre + u1;
    if (c0 + 3 < NCHUNK) cpre[c0 + 3] = pre + u2;
    if (t == 255) cpre[NCHUNK] = x + wpre;   // grand total
    __syncthreads();
    int total = cpre[NCHUNK];
    if (total > CAPC) total = CAPC;     // safety (11-sigma; never hit)
    // 3) copy segments into stage
    for (int c = t; c < NCHUNK; c += 256) {
        int lo = clo[c];
        int n = clen[c];
        int p = cpre[c];
        if (p + n > CAPC) n = (p < CAPC) ? (CAPC - p) : 0;
        const int* seg = ebuf + (size_t)c * CE + lo;
        for (int k = 0; k < n; ++k) stage[p + k] = seg[k];
    }
    __syncthreads();
    // 4) per-node degree count + wave scan over 128 (1 barrier)
    for (int e = t; e < total; e += 256)
        atomicAdd(&cnt[stage[e] & (NPB - 1)], 1);
    __syncthreads();
    int dval = (t < NPB) ? cnt[t] : 0;
    int dx = wave_iscan(dval, lane);
    if (lane == 63) wsum[wid] = dx;
    __syncthreads();
    if (t < NPB) {
        int p2 = dx + ((t >= 64) ? wsum[0] : 0);  // inclusive over [0..t]
        sc2[t + 1] = p2;
    }
    __syncthreads();
    const int nval = min(NPB, NN - base);
    if (t < nval) {
        rpd[base + t] = ((uint32)(b * CAPC + sc2[t]) << 9) | (uint32)min(cnt[t], 511);
        norm[base + t] = rsqrtf(fmaxf((float)cnt[t], 1.0f));
    }
    __syncthreads();
    // 5) bin into csr (byte offsets of 128B feature rows)
    for (int e = t; e < total; e += 256) {
        int v = stage[e];
        int ld = v & (NPB - 1);
        int p = b * CAPC + sc2[ld] + atomicAdd(&lcur[ld], 1);
        csr[p] = v & ~(NPB - 1);            // byte offset = src*128
    }
}

// unpack-accumulate 8 bf16 (uint4) into a0..a7, optional weight
#define ACC8(Rr)                                 \
    a0 += __uint_as_float((Rr).x << 16);         \
    a1 += __uint_as_float((Rr).x & 0xFFFF0000u); \
    a2 += __uint_as_float((Rr).y << 16);         \
    a3 += __uint_as_float((Rr).y & 0xFFFF0000u); \
    a4 += __uint_as_float((Rr).z << 16);         \
    a5 += __uint_as_float((Rr).z & 0xFFFF0000u); \
    a6 += __uint_as_float((Rr).w << 16);         \
    a7 += __uint_as_float((Rr).w & 0xFFFF0000u);

#define ACC8W(Rr, W)                                   \
    a0 += (W) * __uint_as_float((Rr).x << 16);         \
    a1 += (W) * __uint_as_float((Rr).x & 0xFFFF0000u); \
    a2 += (W) * __uint_as_float((Rr).y << 16);         \
    a3 += (W) * __uint_as_float((Rr).y & 0xFFFF0000u); \
    a4 += (W) * __uint_as_float((Rr).z << 16);         \
    a5 += (W) * __uint_as_float((Rr).z & 0xFFFF0000u); \
    a6 += (W) * __uint_as_float((Rr).w << 16);         \
    a7 += (W) * __uint_as_float((Rr).w & 0xFFFF0000u);

#define STEP1(E)                                                           \
    {                                                                      \
        int o_ = csr[(E) + slot];                                          \
        uint4 r_ = *reinterpret_cast<const uint4*>(base + o_ + lo16);      \
        if constexpr (HOP == 1) { float w_ = norm[o_ >> 7]; ACC8W(r_, w_) } \
        else { ACC8(r_) }                                                  \
    }

// ---------- gather hops, node-major 128B rows, csr = byte offsets ----------
// HOP=1: t1[d] = bf16( norm[d]^2 * sum_e norm[s] * g[s] )  -> bf16 outb
// HOP=2: out[d] = norm[d] * sum_e t1[s] + b1               -> f32 outf
// wave = node; 8 edge slots x 8 lanes x 16B. rpd packed: start<<9 | deg.
// XCD-swizzled grid (25000 = 8*3125).
template <int HOP>
__global__ __launch_bounds__(256) void gather_kernel(const unsigned short* __restrict__ in,
                                                     const uint32* __restrict__ rpd,
                                                     const int* __restrict__ csr,
                                                     const float* __restrict__ norm,
                                                     unsigned short* __restrict__ outb,
                                                     float* __restrict__ outf,
                                                     const float* __restrict__ b1) {
    const int grp = (blockIdx.x % NXCD) * (NN / 4 / NXCD) + blockIdx.x / NXCD;
    const int node = grp * 4 + (threadIdx.x >> 6);
    const int lane = threadIdx.x & 63;
    const int slot = lane >> 3;
    const int fo = (lane & 7) * 8;
    const int lo16 = (lane & 7) * 16;
    const char* base = (const char*)in;
    const uint32 v = rpd[node];
    int e = (int)(v >> 9);
    const int e1 = e + (int)(v & 511u);
    float a0 = 0, a1 = 0, a2 = 0, a3 = 0, a4 = 0, a5 = 0, a6 = 0, a7 = 0;
    for (; e + 16 <= e1; e += 16) {
        STEP1(e)
        STEP1(e + 8)
    }
    for (; e + 8 <= e1; e += 8) STEP1(e)
    if (e + slot < e1) STEP1(e)
#pragma unroll
    for (int off = 8; off <= 32; off <<= 1) {
        a0 += __shfl_xor(a0, off); a1 += __shfl_xor(a1, off);
        a2 += __shfl_xor(a2, off); a3 += __shfl_xor(a3, off);
        a4 += __shfl_xor(a4, off); a5 += __shfl_xor(a5, off);
        a6 += __shfl_xor(a6, off); a7 += __shfl_xor(a7, off);
    }
    if (slot == 0) {
        const float nd = norm[node];
        if (HOP == 1) {
            const float sc = nd * nd;
            uint4 o;
            o.x = f2bf(a0 * sc) | (f2bf(a1 * sc) << 16);
            o.y = f2bf(a2 * sc) | (f2bf(a3 * sc) << 16);
            o.z = f2bf(a4 * sc) | (f2bf(a5 * sc) << 16);
            o.w = f2bf(a6 * sc) | (f2bf(a7 * sc) << 16);
            *reinterpret_cast<uint4*>(outb + (size_t)node * D + fo) = o;
        } else {
            float4 bb = *reinterpret_cast<const float4*>(b1 + fo);
            float4 bc = *reinterpret_cast<const float4*>(b1 + fo + 4);
            float4 o1 = {a0 * nd + bb.x, a1 * nd + bb.y, a2 * nd + bb.z, a3 * nd + bb.w};
            float4 o2 = {a4 * nd + bc.x, a5 * nd + bc.y, a6 * nd + bc.z, a7 * nd + bc.w};
            float* op = outf + (size_t)node * D + fo;
            *reinterpret_cast<float4*>(op) = o1;
            *reinterpret_cast<float4*>(op + 4) = o2;
        }
    }
}

extern "C" void kernel_launch(void* const* d_in, const int* in_sizes, int n_in,
                              void* d_out, int out_size, void* d_ws, size_t ws_size,
                              hipStream_t stream) {
    const float* feat = (const float*)d_in[0];
    const int* src    = (const int*)d_in[1];
    const int* dst    = (const int*)d_in[2];
    const float* W1   = (const float*)d_in[3];
    const float* b1   = (const float*)d_in[4];
    float* out        = (float*)d_out;

    // ws layout (4B units), total ~24.7 MB, NO memset needed:
    // rpd[NN] | norm[NN] | basG[1000*783] | csr[782*2560] | union{ ebuf[NE], t1b }
    // fb (bf16 g-table, 12.8MB) lives in d_out — dead until gather2 rewrites d_out.
    uint32*         rpd  = (uint32*)d_ws;
    float*          norm = (float*)(rpd + NN);
    int*            basG = (int*)(norm + NN);
    int*            csr  = basG + (size_t)NCHUNK * BSTR;
    int*            ebuf = csr + (size_t)NBUCK * CAPC;
    unsigned short* t1b  = (unsigned short*)ebuf;
    unsigned short* fb   = (unsigned short*)d_out;

    // fused: chunk-local bucket sort (blocks 0..999) + fcvt (blocks 1000..)
    build_kernel<<<NCHUNK + NFC, 256, 0, stream>>>(feat, W1, fb, src, dst, basG, ebuf);
    // per-bucket: segment assembly + degrees/norm/rpd + csr binning (XCD-swizzled)
    bucketize_kernel<<<NBUCK, 256, 0, stream>>>(ebuf, basG, csr, rpd, norm);

    // hop 1: t1b = bf16(norm_d^2 * sum norm_s * g[s])   (t1b aliases dead ebuf)
    gather_kernel<1><<<NN / 4, 256, 0, stream>>>(fb, rpd, csr, norm, t1b, nullptr, nullptr);
    // hop 2: out = norm_d * sum t1b[s] + b1  (f32, final — fully overwrites d_out)
    gather_kernel<2><<<NN / 4, 256, 0, stream>>>(t1b, rpd, csr, norm, nullptr, out, b1);
}

// Round 18
// 129.075 us; speedup vs baseline: 1.0646x; 1.0646x over previous
//
#include <hip/hip_runtime.h>

#define NN 100000
#define NE 1600000
#define D 64
#define BSHIFT 7
#define NPB 128                        // nodes per bucket
#define NBUCK ((NN + NPB - 1) / NPB)   // 782
#define NCHUNK 1000                    // edge chunks
#define CE (NE / NCHUNK)               // 1600 edges per chunk (exact)
#define BSTR (NBUCK + 1)               // basG row stride (783)
#define BASG_PAD 783008                // 1000*783=783000 rounded up to 128B multiple
#define CAPC 2560                      // csr per-bucket capacity (mean 2046, 11-sigma)
#define NFC 1563                       // fcvt tile-groups (6250 16-node tiles / 4)
#define NXCD 8

typedef unsigned int uint32;
typedef __attribute__((ext_vector_type(8))) short bf16x8;
typedef __attribute__((ext_vector_type(4))) float f32x4;

// 128B-alignment invariants for the 128B-row tables (t1b) — keep these true!
static_assert((NN * 4) % 128 == 0, "rpd/norm region");
static_assert((BASG_PAD * 4) % 128 == 0, "basG region");
static_assert(((size_t)NBUCK * CAPC * 4) % 128 == 0, "csr region");

__device__ __forceinline__ uint32 f2bf(float f) {   // round-to-nearest-even
    union { float f; uint32 i; } c; c.f = f;
    return (c.i + 0x7FFFu + ((c.i >> 16) & 1u)) >> 16;
}

__device__ __forceinline__ bf16x8 cvt8(const float* p) {
    float4 lo = *reinterpret_cast<const float4*>(p);
    float4 hi = *reinterpret_cast<const float4*>(p + 4);
    bf16x8 r;
    r[0] = (short)f2bf(lo.x); r[1] = (short)f2bf(lo.y);
    r[2] = (short)f2bf(lo.z); r[3] = (short)f2bf(lo.w);
    r[4] = (short)f2bf(hi.x); r[5] = (short)f2bf(hi.y);
    r[6] = (short)f2bf(hi.z); r[7] = (short)f2bf(hi.w);
    return r;
}

// intra-wave inclusive scan (64 lanes)
__device__ __forceinline__ int wave_iscan(int x, int lane) {
#pragma unroll
    for (int off = 1; off < 64; off <<= 1) {
        int y = __shfl_up(x, off);
        if (lane >= off) x += y;
    }
    return x;
}

// bijective chunked block->XCD swizzle [T1, m204]
__device__ __forceinline__ int swz_chunked(int bid, int nwg) {
    int q = nwg / NXCD, r = nwg % NXCD;
    int xcd = bid % NXCD, idx = bid / NXCD;
    return (xcd < r) ? xcd * (q + 1) + idx : r * (q + 1) + (xcd - r) * q + idx;
}

// ---------- FUSED: chunk-local bucket sort (blocks 0..NCHUNK-1) + fcvt ----------
__global__ __launch_bounds__(256) void build_kernel(const float* __restrict__ feat,
                                                    const float* __restrict__ W1,
                                                    unsigned short* __restrict__ fb,
                                                    const int* __restrict__ src,
                                                    const int* __restrict__ dst,
                                                    int* __restrict__ basG,
                                                    int* __restrict__ ebuf) {
    __shared__ int ebl[CE];                 // packed (src<<7 | localdst)
    __shared__ unsigned short bkt[CE];      // bucket id per staged edge
    __shared__ int cnt[NBUCK];              // per-bucket count, then scatter cursor
    __shared__ int sc[NBUCK + 1];           // exclusive scan of cnt
    __shared__ int wsum[4];
    const int bid = blockIdx.x;
    const int t = threadIdx.x;
    if (bid >= NCHUNK) {                   // ---- fcvt half ----
        const int wid = t >> 6;
        const int lane = t & 63;
        const int tile = (bid - NCHUNK) * 4 + wid;
        if (tile >= 6250) return;
        const int node0 = tile * 16;
        const int m = lane & 15;
        const int kg = lane >> 4;
        const float* frow = feat + (size_t)(node0 + m) * D + kg * 8;
        bf16x8 aF0 = cvt8(frow);
        bf16x8 aF1 = cvt8(frow + 32);
#pragma unroll
        for (int tt = 0; tt < 4; ++tt) {
            const float* wrow = W1 + (size_t)(tt * 16 + m) * D + kg * 8;
            bf16x8 bF0 = cvt8(wrow);
            bf16x8 bF1 = cvt8(wrow + 32);
            f32x4 acc = {0.f, 0.f, 0.f, 0.f};
            acc = __builtin_amdgcn_mfma_f32_16x16x32_bf16(aF0, bF0, acc, 0, 0, 0);
            acc = __builtin_amdgcn_mfma_f32_16x16x32_bf16(aF1, bF1, acc, 0, 0, 0);
            const int col = tt * 16 + m;
#pragma unroll
            for (int r = 0; r < 4; ++r)
                fb[(size_t)(node0 + kg * 4 + r) * D + col] = (unsigned short)f2bf(acc[r]);
        }
        return;
    }
    // ---- part half ----
    const int lane = t & 63;
    const int wid = t >> 6;
    for (int i = t; i < NBUCK; i += 256) cnt[i] = 0;
    __syncthreads();
    const int e0 = bid * CE;
    for (int i = t; i < CE; i += 256) {
        int d = dst[e0 + i], s = src[e0 + i];
        int b = d >> BSHIFT;
        ebl[i] = (s << BSHIFT) | (d & (NPB - 1));
        bkt[i] = (unsigned short)b;
        atomicAdd(&cnt[b], 1);
    }
    __syncthreads();
    // exclusive scan of cnt[0..781]: 4/thread + wave-shuffle scan (1 barrier)
    const int j0 = t * 4;
    int v0 = (j0 + 0 < NBUCK) ? cnt[j0 + 0] : 0;
    int v1 = (j0 + 1 < NBUCK) ? cnt[j0 + 1] : 0;
    int v2 = (j0 + 2 < NBUCK) ? cnt[j0 + 2] : 0;
    int v3 = (j0 + 3 < NBUCK) ? cnt[j0 + 3] : 0;
    int s0 = v0, s1 = s0 + v1, s2 = s1 + v2, s3 = s2 + v3;
    int x = wave_iscan(s3, lane);
    if (lane == 63) wsum[wid] = x;
    __syncthreads();
    int wpre = 0;
    for (int w = 0; w < wid; ++w) wpre += wsum[w];
    const int pre = x + wpre - s3;          // exclusive thread prefix
    if (j0 + 0 < NBUCK) sc[j0 + 0] = pre;
    if (j0 + 1 < NBUCK) sc[j0 + 1] = pre + s0;
    if (j0 + 2 < NBUCK) sc[j0 + 2] = pre + s1;
    if (j0 + 3 < NBUCK) sc[j0 + 3] = pre + s2;
    if (t == 0) sc[NBUCK] = CE;
    __syncthreads();
    // emit local prefix table (coalesced) + reset cnt as scatter cursor
    int* brow = basG + (size_t)bid * BSTR;
    for (int j = t; j < BSTR; j += 256) brow[j] = sc[j];
    for (int i = t; i < NBUCK; i += 256) cnt[i] = 0;
    __syncthreads();
    // scatter bucket-sorted into own chunk region (writes land in 6.4KB window)
    for (int i = t; i < CE; i += 256) {
        int b = bkt[i];
        int p = sc[b] + atomicAdd(&cnt[b], 1);
        ebuf[e0 + p] = ebl[i];
    }
}

// ---------- per-bucket: assemble segments, degrees/norm/rpd, bin to csr ----------
__global__ __launch_bounds__(256) void bucketize_kernel(const int* __restrict__ ebuf,
                                                        const int* __restrict__ basG,
                                                        int* __restrict__ csr,
                                                        uint32* __restrict__ rpd,
                                                        float* __restrict__ norm) {
    __shared__ int stage[CAPC];
    __shared__ int clo[NCHUNK];
    __shared__ int clen[NCHUNK];
    __shared__ int cpre[NCHUNK + 1];
    __shared__ int wsum[4];
    __shared__ int cnt[NPB];
    __shared__ int sc2[NPB + 1];
    __shared__ int lcur[NPB];
    const int b = swz_chunked(blockIdx.x, NBUCK);
    const int base = b << BSHIFT;
    const int t = threadIdx.x;
    const int lane = t & 63;
    const int wid = t >> 6;
    // 1) per-chunk segment ranges for this bucket
    for (int c = t; c < NCHUNK; c += 256) {
        int lo = basG[(size_t)c * BSTR + b];
        int hi = basG[(size_t)c * BSTR + b + 1];
        clo[c] = lo;
        clen[c] = hi - lo;
    }
    if (t < NPB) { cnt[t] = 0; lcur[t] = 0; }
    if (t == 0) sc2[0] = 0;
    __syncthreads();
    // 2) exclusive scan of clen[0..NCHUNK-1]: 4/thread + wave scan (1 barrier)
    const int c0 = t * 4;
    int w0 = (c0 + 0 < NCHUNK) ? clen[c0 + 0] : 0;
    int w1 = (c0 + 1 < NCHUNK) ? clen[c0 + 1] : 0;
    int w2 = (c0 + 2 < NCHUNK) ? clen[c0 + 2] : 0;
    int w3 = (c0 + 3 < NCHUNK) ? clen[c0 + 3] : 0;
    int u0 = w0, u1 = u0 + w1, u2 = u1 + w2, u3 = u2 + w3;
    int x = wave_iscan(u3, lane);
    if (lane == 63) wsum[wid] = x;
    __syncthreads();
    int wpre = 0;
    for (int w = 0; w < wid; ++w) wpre += wsum[w];
    const int pre = x + wpre - u3;
    if (c0 + 0 < NCHUNK) cpre[c0 + 0] = pre;
    if (c0 + 1 < NCHUNK) cpre[c0 + 1] = pre + u0;
    if (c0 + 2 < NCHUNK) cpre[c0 + 2] = pre + u1;
    if (c0 + 3 < NCHUNK) cpre[c0 + 3] = pre + u2;
    if (t == 255) cpre[NCHUNK] = x + wpre;   // grand total
    __syncthreads();
    int total = cpre[NCHUNK];
    if (total > CAPC) total = CAPC;     // safety (11-sigma; never hit)
    // 3) copy segments into stage
    for (int c = t; c < NCHUNK; c += 256) {
        int lo = clo[c];
        int n = clen[c];
        int p = cpre[c];
        if (p + n > CAPC) n = (p < CAPC) ? (CAPC - p) : 0;
        const int* seg = ebuf + (size_t)c * CE + lo;
        for (int k = 0; k < n; ++k) stage[p + k] = seg[k];
    }
    __syncthreads();
    // 4) per-node degree count + wave scan over 128 (1 barrier)
    for (int e = t; e < total; e += 256)
        atomicAdd(&cnt[stage[e] & (NPB - 1)], 1);
    __syncthreads();
    int dval = (t < NPB) ? cnt[t] : 0;
    int dx = wave_iscan(dval, lane);
    if (lane == 63) wsum[wid] = dx;
    __syncthreads();
    if (t < NPB) {
        int p2 = dx + ((t >= 64) ? wsum[0] : 0);  // inclusive over [0..t]
        sc2[t + 1] = p2;
    }
    __syncthreads();
    const int nval = min(NPB, NN - base);
    if (t < nval) {
        rpd[base + t] = ((uint32)(b * CAPC + sc2[t]) << 9) | (uint32)min(cnt[t], 511);
        norm[base + t] = rsqrtf(fmaxf((float)cnt[t], 1.0f));
    }
    __syncthreads();
    // 5) bin into csr (byte offsets of 128B feature rows)
    for (int e = t; e < total; e += 256) {
        int v = stage[e];
        int ld = v & (NPB - 1);
        int p = b * CAPC + sc2[ld] + atomicAdd(&lcur[ld], 1);
        csr[p] = v & ~(NPB - 1);            // byte offset = src*128
    }
}

// unpack-accumulate 8 bf16 (uint4) into a0..a7, optional weight
#define ACC8(Rr)                                 \
    a0 += __uint_as_float((Rr).x << 16);         \
    a1 += __uint_as_float((Rr).x & 0xFFFF0000u); \
    a2 += __uint_as_float((Rr).y << 16);         \
    a3 += __uint_as_float((Rr).y & 0xFFFF0000u); \
    a4 += __uint_as_float((Rr).z << 16);         \
    a5 += __uint_as_float((Rr).z & 0xFFFF0000u); \
    a6 += __uint_as_float((Rr).w << 16);         \
    a7 += __uint_as_float((Rr).w & 0xFFFF0000u);

#define ACC8W(Rr, W)                                   \
    a0 += (W) * __uint_as_float((Rr).x << 16);         \
    a1 += (W) * __uint_as_float((Rr).x & 0xFFFF0000u); \
    a2 += (W) * __uint_as_float((Rr).y << 16);         \
    a3 += (W) * __uint_as_float((Rr).y & 0xFFFF0000u); \
    a4 += (W) * __uint_as_float((Rr).z << 16);         \
    a5 += (W) * __uint_as_float((Rr).z & 0xFFFF0000u); \
    a6 += (W) * __uint_as_float((Rr).w << 16);         \
    a7 += (W) * __uint_as_float((Rr).w & 0xFFFF0000u);

#define STEP1(E)                                                           \
    {                                                                      \
        int o_ = csr[(E) + slot];                                          \
        uint4 r_ = *reinterpret_cast<const uint4*>(base + o_ + lo16);      \
        if constexpr (HOP == 1) { float w_ = norm[o_ >> 7]; ACC8W(r_, w_) } \
        else { ACC8(r_) }                                                  \
    }

// ---------- gather hops, node-major 128B rows, csr = byte offsets ----------
// HOP=1: t1[d] = bf16( norm[d]^2 * sum_e norm[s] * g[s] )  -> bf16 outb
// HOP=2: out[d] = norm[d] * sum_e t1[s] + b1               -> f32 outf
// wave = node; 8 edge slots x 8 lanes x 16B. rpd packed: start<<9 | deg.
// XCD-swizzled grid (25000 = 8*3125).
template <int HOP>
__global__ __launch_bounds__(256) void gather_kernel(const unsigned short* __restrict__ in,
                                                     const uint32* __restrict__ rpd,
                                                     const int* __restrict__ csr,
                                                     const float* __restrict__ norm,
                                                     unsigned short* __restrict__ outb,
                                                     float* __restrict__ outf,
                                                     const float* __restrict__ b1) {
    const int grp = (blockIdx.x % NXCD) * (NN / 4 / NXCD) + blockIdx.x / NXCD;
    const int node = grp * 4 + (threadIdx.x >> 6);
    const int lane = threadIdx.x & 63;
    const int slot = lane >> 3;
    const int fo = (lane & 7) * 8;
    const int lo16 = (lane & 7) * 16;
    const char* base = (const char*)in;
    const uint32 v = rpd[node];
    int e = (int)(v >> 9);
    const int e1 = e + (int)(v & 511u);
    float a0 = 0, a1 = 0, a2 = 0, a3 = 0, a4 = 0, a5 = 0, a6 = 0, a7 = 0;
    for (; e + 16 <= e1; e += 16) {
        STEP1(e)
        STEP1(e + 8)
    }
    for (; e + 8 <= e1; e += 8) STEP1(e)
    if (e + slot < e1) STEP1(e)
#pragma unroll
    for (int off = 8; off <= 32; off <<= 1) {
        a0 += __shfl_xor(a0, off); a1 += __shfl_xor(a1, off);
        a2 += __shfl_xor(a2, off); a3 += __shfl_xor(a3, off);
        a4 += __shfl_xor(a4, off); a5 += __shfl_xor(a5, off);
        a6 += __shfl_xor(a6, off); a7 += __shfl_xor(a7, off);
    }
    if (slot == 0) {
        const float nd = norm[node];
        if (HOP == 1) {
            const float sc = nd * nd;
            uint4 o;
            o.x = f2bf(a0 * sc) | (f2bf(a1 * sc) << 16);
            o.y = f2bf(a2 * sc) | (f2bf(a3 * sc) << 16);
            o.z = f2bf(a4 * sc) | (f2bf(a5 * sc) << 16);
            o.w = f2bf(a6 * sc) | (f2bf(a7 * sc) << 16);
            *reinterpret_cast<uint4*>(outb + (size_t)node * D + fo) = o;
        } else {
            float4 bb = *reinterpret_cast<const float4*>(b1 + fo);
            float4 bc = *reinterpret_cast<const float4*>(b1 + fo + 4);
            float4 o1 = {a0 * nd + bb.x, a1 * nd + bb.y, a2 * nd + bb.z, a3 * nd + bb.w};
            float4 o2 = {a4 * nd + bc.x, a5 * nd + bc.y, a6 * nd + bc.z, a7 * nd + bc.w};
            float* op = outf + (size_t)node * D + fo;
            *reinterpret_cast<float4*>(op) = o1;
            *reinterpret_cast<float4*>(op + 4) = o2;
        }
    }
}

extern "C" void kernel_launch(void* const* d_in, const int* in_sizes, int n_in,
                              void* d_out, int out_size, void* d_ws, size_t ws_size,
                              hipStream_t stream) {
    const float* feat = (const float*)d_in[0];
    const int* src    = (const int*)d_in[1];
    const int* dst    = (const int*)d_in[2];
    const float* W1   = (const float*)d_in[3];
    const float* b1   = (const float*)d_in[4];
    float* out        = (float*)d_out;

    // ws layout (4B units) — every region size is a multiple of 32 ints (128B)
    // so t1b's 128B rows stay line-aligned (r17 regression: basG 783000 broke this):
    // rpd[NN] | norm[NN] | basG[BASG_PAD] | csr[NBUCK*CAPC] | union{ ebuf[NE], t1b }
    // fb (bf16 g-table, 12.8MB) lives in d_out — dead until gather2 rewrites d_out.
    uint32*         rpd  = (uint32*)d_ws;
    float*          norm = (float*)(rpd + NN);
    int*            basG = (int*)(norm + NN);
    int*            csr  = basG + BASG_PAD;
    int*            ebuf = csr + (size_t)NBUCK * CAPC;
    unsigned short* t1b  = (unsigned short*)ebuf;
    unsigned short* fb   = (unsigned short*)d_out;

    // fused: chunk-local bucket sort (blocks 0..999) + fcvt (blocks 1000..)
    build_kernel<<<NCHUNK + NFC, 256, 0, stream>>>(feat, W1, fb, src, dst, basG, ebuf);
    // per-bucket: segment assembly + degrees/norm/rpd + csr binning (XCD-swizzled)
    bucketize_kernel<<<NBUCK, 256, 0, stream>>>(ebuf, basG, csr, rpd, norm);

    // hop 1: t1b = bf16(norm_d^2 * sum norm_s * g[s])   (t1b aliases dead ebuf)
    gather_kernel<1><<<NN / 4, 256, 0, stream>>>(fb, rpd, csr, norm, t1b, nullptr, nullptr);
    // hop 2: out = norm_d * sum t1b[s] + b1  (f32, final — fully overwrites d_out)
    gather_kernel<2><<<NN / 4, 256, 0, stream>>>(t1b, rpd, csr, norm, nullptr, out, b1);
}

// Round 19
// 123.691 us; speedup vs baseline: 1.1109x; 1.0435x over previous
//
#include <hip/hip_runtime.h>

#define NN 100000
#define NE 1600000
#define D 64
#define BSHIFT 7
#define NPB 128                        // nodes per bucket
#define NBUCK ((NN + NPB - 1) / NPB)   // 782
#define NCHUNK 1000                    // edge chunks
#define CE (NE / NCHUNK)               // 1600 edges per chunk (exact)
#define BSTR (NBUCK + 1)               // basG row stride (783)
#define BASG_PAD 783008                // 1000*783 rounded up to 128B multiple
#define CAPC 2560                      // csr per-bucket capacity (mean 2046, 11-sigma)
#define NFC 1563                       // fcvt tile-groups (6250 16-node tiles / 4)
#define NXCD 8
#define NSL 8                          // src slices (src>>14 in 0..6)

typedef unsigned int uint32;
typedef __attribute__((ext_vector_type(8))) short bf16x8;
typedef __attribute__((ext_vector_type(4))) float f32x4;

// 128B-alignment invariants for the 128B-row tables (t1b) — keep these true!
static_assert((NN * 4) % 128 == 0, "rpd/norm region");
static_assert((BASG_PAD * 4) % 128 == 0, "basG region");
static_assert(((size_t)NBUCK * CAPC * 4) % 128 == 0, "csr region");

__device__ __forceinline__ uint32 f2bf(float f) {   // round-to-nearest-even
    union { float f; uint32 i; } c; c.f = f;
    return (c.i + 0x7FFFu + ((c.i >> 16) & 1u)) >> 16;
}

__device__ __forceinline__ bf16x8 cvt8(const float* p) {
    float4 lo = *reinterpret_cast<const float4*>(p);
    float4 hi = *reinterpret_cast<const float4*>(p + 4);
    bf16x8 r;
    r[0] = (short)f2bf(lo.x); r[1] = (short)f2bf(lo.y);
    r[2] = (short)f2bf(lo.z); r[3] = (short)f2bf(lo.w);
    r[4] = (short)f2bf(hi.x); r[5] = (short)f2bf(hi.y);
    r[6] = (short)f2bf(hi.z); r[7] = (short)f2bf(hi.w);
    return r;
}

// intra-wave inclusive scan (64 lanes)
__device__ __forceinline__ int wave_iscan(int x, int lane) {
#pragma unroll
    for (int off = 1; off < 64; off <<= 1) {
        int y = __shfl_up(x, off);
        if (lane >= off) x += y;
    }
    return x;
}

// bijective chunked block->XCD swizzle [T1, m204]
__device__ __forceinline__ int swz_chunked(int bid, int nwg) {
    int q = nwg / NXCD, r = nwg % NXCD;
    int xcd = bid % NXCD, idx = bid / NXCD;
    return (xcd < r) ? xcd * (q + 1) + idx : r * (q + 1) + (xcd - r) * q + idx;
}

// ---------- FUSED: chunk-local bucket sort (blocks 0..NCHUNK-1) + fcvt ----------
__global__ __launch_bounds__(256) void build_kernel(const float* __restrict__ feat,
                                                    const float* __restrict__ W1,
                                                    unsigned short* __restrict__ fb,
                                                    const int* __restrict__ src,
                                                    const int* __restrict__ dst,
                                                    int* __restrict__ basG,
                                                    int* __restrict__ ebuf) {
    __shared__ int ebl[CE];                 // packed (src<<7 | localdst)
    __shared__ unsigned short bkt[CE];      // bucket id per staged edge
    __shared__ int cnt[NBUCK];              // per-bucket count, then scatter cursor
    __shared__ int sc[NBUCK + 1];           // exclusive scan of cnt
    __shared__ int wsum[4];
    const int bid = blockIdx.x;
    const int t = threadIdx.x;
    if (bid >= NCHUNK) {                   // ---- fcvt half ----
        const int wid = t >> 6;
        const int lane = t & 63;
        const int tile = (bid - NCHUNK) * 4 + wid;
        if (tile >= 6250) return;
        const int node0 = tile * 16;
        const int m = lane & 15;
        const int kg = lane >> 4;
        const float* frow = feat + (size_t)(node0 + m) * D + kg * 8;
        bf16x8 aF0 = cvt8(frow);
        bf16x8 aF1 = cvt8(frow + 32);
#pragma unroll
        for (int tt = 0; tt < 4; ++tt) {
            const float* wrow = W1 + (size_t)(tt * 16 + m) * D + kg * 8;
            bf16x8 bF0 = cvt8(wrow);
            bf16x8 bF1 = cvt8(wrow + 32);
            f32x4 acc = {0.f, 0.f, 0.f, 0.f};
            acc = __builtin_amdgcn_mfma_f32_16x16x32_bf16(aF0, bF0, acc, 0, 0, 0);
            acc = __builtin_amdgcn_mfma_f32_16x16x32_bf16(aF1, bF1, acc, 0, 0, 0);
            const int col = tt * 16 + m;
#pragma unroll
            for (int r = 0; r < 4; ++r)
                fb[(size_t)(node0 + kg * 4 + r) * D + col] = (unsigned short)f2bf(acc[r]);
        }
        return;
    }
    // ---- part half ----
    const int lane = t & 63;
    const int wid = t >> 6;
    for (int i = t; i < NBUCK; i += 256) cnt[i] = 0;
    __syncthreads();
    const int e0 = bid * CE;
    for (int i = t; i < CE; i += 256) {
        int d = dst[e0 + i], s = src[e0 + i];
        int b = d >> BSHIFT;
        ebl[i] = (s << BSHIFT) | (d & (NPB - 1));
        bkt[i] = (unsigned short)b;
        atomicAdd(&cnt[b], 1);
    }
    __syncthreads();
    // exclusive scan of cnt[0..781]: 4/thread + wave-shuffle scan (1 barrier)
    const int j0 = t * 4;
    int v0 = (j0 + 0 < NBUCK) ? cnt[j0 + 0] : 0;
    int v1 = (j0 + 1 < NBUCK) ? cnt[j0 + 1] : 0;
    int v2 = (j0 + 2 < NBUCK) ? cnt[j0 + 2] : 0;
    int v3 = (j0 + 3 < NBUCK) ? cnt[j0 + 3] : 0;
    int s0 = v0, s1 = s0 + v1, s2 = s1 + v2, s3 = s2 + v3;
    int x = wave_iscan(s3, lane);
    if (lane == 63) wsum[wid] = x;
    __syncthreads();
    int wpre = 0;
    for (int w = 0; w < wid; ++w) wpre += wsum[w];
    const int pre = x + wpre - s3;          // exclusive thread prefix
    if (j0 + 0 < NBUCK) sc[j0 + 0] = pre;
    if (j0 + 1 < NBUCK) sc[j0 + 1] = pre + s0;
    if (j0 + 2 < NBUCK) sc[j0 + 2] = pre + s1;
    if (j0 + 3 < NBUCK) sc[j0 + 3] = pre + s2;
    if (t == 0) sc[NBUCK] = CE;
    __syncthreads();
    // emit local prefix table (coalesced) + reset cnt as scatter cursor
    int* brow = basG + (size_t)bid * BSTR;
    for (int j = t; j < BSTR; j += 256) brow[j] = sc[j];
    for (int i = t; i < NBUCK; i += 256) cnt[i] = 0;
    __syncthreads();
    // scatter bucket-sorted into own chunk region
    for (int i = t; i < CE; i += 256) {
        int b = bkt[i];
        int p = sc[b] + atomicAdd(&cnt[b], 1);
        ebuf[e0 + p] = ebl[i];
    }
}

// ---------- per-bucket: assemble segments; bin by (node, src-slice) ----------
// csr rows become contiguous per node with edges ordered by src slice (src>>14)
// -> gathers sweep the feature table front-to-back => L2-sized working set.
__global__ __launch_bounds__(256) void bucketize_kernel(const int* __restrict__ ebuf,
                                                        const int* __restrict__ basG,
                                                        int* __restrict__ csr,
                                                        uint32* __restrict__ rpd,
                                                        float* __restrict__ norm) {
    __shared__ int stage[CAPC];
    __shared__ int clo[NCHUNK];
    __shared__ int clen[NCHUNK];
    __shared__ int cpre[NCHUNK + 1];
    __shared__ int wsum[4];
    __shared__ int cnt2[NPB * NSL];         // (node, slice) counts
    __shared__ int pf[NPB * NSL + 1];       // exclusive prefix
    __shared__ int lcur2[NPB * NSL];        // scatter cursors
    const int b = swz_chunked(blockIdx.x, NBUCK);
    const int base = b << BSHIFT;
    const int t = threadIdx.x;
    const int lane = t & 63;
    const int wid = t >> 6;
    // 1) per-chunk segment ranges for this bucket
    for (int c = t; c < NCHUNK; c += 256) {
        int lo = basG[(size_t)c * BSTR + b];
        int hi = basG[(size_t)c * BSTR + b + 1];
        clo[c] = lo;
        clen[c] = hi - lo;
    }
    for (int i = t; i < NPB * NSL; i += 256) { cnt2[i] = 0; lcur2[i] = 0; }
    __syncthreads();
    // 2) exclusive scan of clen[0..NCHUNK-1]: 4/thread + wave scan
    const int c0 = t * 4;
    int w0 = (c0 + 0 < NCHUNK) ? clen[c0 + 0] : 0;
    int w1 = (c0 + 1 < NCHUNK) ? clen[c0 + 1] : 0;
    int w2 = (c0 + 2 < NCHUNK) ? clen[c0 + 2] : 0;
    int w3 = (c0 + 3 < NCHUNK) ? clen[c0 + 3] : 0;
    int u0 = w0, u1 = u0 + w1, u2 = u1 + w2, u3 = u2 + w3;
    int x = wave_iscan(u3, lane);
    if (lane == 63) wsum[wid] = x;
    __syncthreads();
    int wpre = 0;
    for (int w = 0; w < wid; ++w) wpre += wsum[w];
    const int pre = x + wpre - u3;
    if (c0 + 0 < NCHUNK) cpre[c0 + 0] = pre;
    if (c0 + 1 < NCHUNK) cpre[c0 + 1] = pre + u0;
    if (c0 + 2 < NCHUNK) cpre[c0 + 2] = pre + u1;
    if (c0 + 3 < NCHUNK) cpre[c0 + 3] = pre + u2;
    if (t == 255) cpre[NCHUNK] = x + wpre;   // grand total
    __syncthreads();
    int total = cpre[NCHUNK];
    if (total > CAPC) total = CAPC;     // safety (11-sigma; never hit)
    // 3) copy segments into stage + count (node, slice)
    for (int c = t; c < NCHUNK; c += 256) {
        int lo = clo[c];
        int n = clen[c];
        int p = cpre[c];
        if (p + n > CAPC) n = (p < CAPC) ? (CAPC - p) : 0;
        const int* seg = ebuf + (size_t)c * CE + lo;
        for (int k = 0; k < n; ++k) stage[p + k] = seg[k];
    }
    __syncthreads();
    for (int e = t; e < total; e += 256) {
        int v = stage[e];
        atomicAdd(&cnt2[(v & (NPB - 1)) * NSL + (v >> 21)], 1);
    }
    __syncthreads();
    // 4) exclusive scan of the 1024 (node,slice) bins: 4/thread (exact)
    const int k0 = t * 4;
    int q0 = cnt2[k0 + 0], q1 = cnt2[k0 + 1], q2 = cnt2[k0 + 2], q3 = cnt2[k0 + 3];
    int r0 = q0, r1 = r0 + q1, r2 = r1 + q2, r3 = r2 + q3;
    int y = wave_iscan(r3, lane);
    if (lane == 63) wsum[wid] = y;
    __syncthreads();
    int wp2 = 0;
    for (int w = 0; w < wid; ++w) wp2 += wsum[w];
    const int pe = y + wp2 - r3;
    pf[k0 + 0] = pe;
    pf[k0 + 1] = pe + r0;
    pf[k0 + 2] = pe + r1;
    pf[k0 + 3] = pe + r2;
    if (t == 255) pf[NPB * NSL] = y + wp2;
    __syncthreads();
    const int nval = min(NPB, NN - base);
    if (t < nval) {
        int st = pf[t * NSL];
        int deg = pf[(t + 1) * NSL] - st;
        rpd[base + t] = ((uint32)(b * CAPC + st) << 9) | (uint32)min(deg, 511);
        norm[base + t] = rsqrtf(fmaxf((float)deg, 1.0f));
    }
    __syncthreads();
    // 5) bin into csr (byte offsets), slice-ordered within each node's row
    for (int e = t; e < total; e += 256) {
        int v = stage[e];
        int key = (v & (NPB - 1)) * NSL + (v >> 21);
        int p = b * CAPC + pf[key] + atomicAdd(&lcur2[key], 1);
        csr[p] = v & ~(NPB - 1);            // byte offset = src*128
    }
}

// unpack-accumulate 8 bf16 (uint4) into a0..a7, optional weight
#define ACC8(Rr)                                 \
    a0 += __uint_as_float((Rr).x << 16);         \
    a1 += __uint_as_float((Rr).x & 0xFFFF0000u); \
    a2 += __uint_as_float((Rr).y << 16);         \
    a3 += __uint_as_float((Rr).y & 0xFFFF0000u); \
    a4 += __uint_as_float((Rr).z << 16);         \
    a5 += __uint_as_float((Rr).z & 0xFFFF0000u); \
    a6 += __uint_as_float((Rr).w << 16);         \
    a7 += __uint_as_float((Rr).w & 0xFFFF0000u);

#define ACC8W(Rr, W)                                   \
    a0 += (W) * __uint_as_float((Rr).x << 16);         \
    a1 += (W) * __uint_as_float((Rr).x & 0xFFFF0000u); \
    a2 += (W) * __uint_as_float((Rr).y << 16);         \
    a3 += (W) * __uint_as_float((Rr).y & 0xFFFF0000u); \
    a4 += (W) * __uint_as_float((Rr).z << 16);         \
    a5 += (W) * __uint_as_float((Rr).z & 0xFFFF0000u); \
    a6 += (W) * __uint_as_float((Rr).w << 16);         \
    a7 += (W) * __uint_as_float((Rr).w & 0xFFFF0000u);

#define STEP1(E)                                                           \
    {                                                                      \
        int o_ = csr[(E)];                                                 \
        uint4 r_ = *reinterpret_cast<const uint4*>(base + o_ + lo16);      \
        if constexpr (HOP == 1) { float w_ = norm[o_ >> 7]; ACC8W(r_, w_) } \
        else { ACC8(r_) }                                                  \
    }

// ---------- gather hops: TWO nodes per wave, 4 edge slots each ----------
// Lanes 0-31 -> nodeA, lanes 32-63 -> nodeB; slot = (lane>>3)&3; 8 rows in
// flight per wave. Rows are slice-ordered, 4 edges/node/step -> the chip
// sweeps the table front-to-back (instantaneous window ~3 MB, L2-resident).
// HOP=1: t1[d] = bf16( norm[d]^2 * sum_e norm[s] * g[s] )  -> bf16 outb
// HOP=2: out[d] = norm[d] * sum_e t1[s] + b1               -> f32 outf
template <int HOP>
__global__ __launch_bounds__(256) void gather_kernel(const unsigned short* __restrict__ in,
                                                     const uint32* __restrict__ rpd,
                                                     const int* __restrict__ csr,
                                                     const float* __restrict__ norm,
                                                     unsigned short* __restrict__ outb,
                                                     float* __restrict__ outf,
                                                     const float* __restrict__ b1) {
    const int grp = swz_chunked(blockIdx.x, NN / 8);
    const int lane = threadIdx.x & 63;
    const int node = grp * 8 + (threadIdx.x >> 6) * 2 + (lane >> 5);
    const int slot = (lane >> 3) & 3;       // edge slot within my node
    const int fo = (lane & 7) * 8;
    const int lo16 = (lane & 7) * 16;
    const char* base = (const char*)in;
    const uint32 v = rpd[node];
    int e = (int)(v >> 9) + slot;
    const int e1 = (int)(v >> 9) + (int)(v & 511u);
    float a0 = 0, a1 = 0, a2 = 0, a3 = 0, a4 = 0, a5 = 0, a6 = 0, a7 = 0;
    for (; e < e1; e += 4) STEP1(e)
    // reduce over the 4 slots within each 32-lane half (bits 3,4 of lane)
#pragma unroll
    for (int off = 8; off <= 16; off <<= 1) {
        a0 += __shfl_xor(a0, off); a1 += __shfl_xor(a1, off);
        a2 += __shfl_xor(a2, off); a3 += __shfl_xor(a3, off);
        a4 += __shfl_xor(a4, off); a5 += __shfl_xor(a5, off);
        a6 += __shfl_xor(a6, off); a7 += __shfl_xor(a7, off);
    }
    if (((lane >> 3) & 3) == 0) {           // slot-0 lanes of each half write
        const float nd = norm[node];
        if (HOP == 1) {
            const float sc = nd * nd;
            uint4 o;
            o.x = f2bf(a0 * sc) | (f2bf(a1 * sc) << 16);
            o.y = f2bf(a2 * sc) | (f2bf(a3 * sc) << 16);
            o.z = f2bf(a4 * sc) | (f2bf(a5 * sc) << 16);
            o.w = f2bf(a6 * sc) | (f2bf(a7 * sc) << 16);
            *reinterpret_cast<uint4*>(outb + (size_t)node * D + fo) = o;
        } else {
            float4 bb = *reinterpret_cast<const float4*>(b1 + fo);
            float4 bc = *reinterpret_cast<const float4*>(b1 + fo + 4);
            float4 o1 = {a0 * nd + bb.x, a1 * nd + bb.y, a2 * nd + bb.z, a3 * nd + bb.w};
            float4 o2 = {a4 * nd + bc.x, a5 * nd + bc.y, a6 * nd + bc.z, a7 * nd + bc.w};
            float* op = outf + (size_t)node * D + fo;
            *reinterpret_cast<float4*>(op) = o1;
            *reinterpret_cast<float4*>(op + 4) = o2;
        }
    }
}

extern "C" void kernel_launch(void* const* d_in, const int* in_sizes, int n_in,
                              void* d_out, int out_size, void* d_ws, size_t ws_size,
                              hipStream_t stream) {
    const float* feat = (const float*)d_in[0];
    const int* src    = (const int*)d_in[1];
    const int* dst    = (const int*)d_in[2];
    const float* W1   = (const float*)d_in[3];
    const float* b1   = (const float*)d_in[4];
    float* out        = (float*)d_out;

    // ws layout (4B units) — every region size is a multiple of 32 ints (128B):
    // rpd[NN] | norm[NN] | basG[BASG_PAD] | csr[NBUCK*CAPC] | union{ ebuf[NE], t1b }
    // fb (bf16 g-table, 12.8MB) lives in d_out — dead until gather2 rewrites d_out.
    uint32*         rpd  = (uint32*)d_ws;
    float*          norm = (float*)(rpd + NN);
    int*            basG = (int*)(norm + NN);
    int*            csr  = basG + BASG_PAD;
    int*            ebuf = csr + (size_t)NBUCK * CAPC;
    unsigned short* t1b  = (unsigned short*)ebuf;
    unsigned short* fb   = (unsigned short*)d_out;

    // fused: chunk-local bucket sort (blocks 0..999) + fcvt (blocks 1000..)
    build_kernel<<<NCHUNK + NFC, 256, 0, stream>>>(feat, W1, fb, src, dst, basG, ebuf);
    // per-bucket: segment assembly + (node,slice)-binned csr + rpd/norm
    bucketize_kernel<<<NBUCK, 256, 0, stream>>>(ebuf, basG, csr, rpd, norm);

    // hop 1: t1b = bf16(norm_d^2 * sum norm_s * g[s])   (t1b aliases dead ebuf)
    gather_kernel<1><<<NN / 8, 256, 0, stream>>>(fb, rpd, csr, norm, t1b, nullptr, nullptr);
    // hop 2: out = norm_d * sum t1b[s] + b1  (f32, final — fully overwrites d_out)
    gather_kernel<2><<<NN / 8, 256, 0, stream>>>(t1b, rpd, csr, norm, nullptr, out, b1);
}